// Round 5
// baseline (377.614 us; speedup 1.0000x reference)
//
#include <hip/hip_runtime.h>

#define EPS 1e-5f
#define NDIM 384
#define CDIM 128
#define NN (NDIM * NDIM)   // 147456

typedef unsigned short ushort_t;
typedef __attribute__((ext_vector_type(8))) short short8;     // 8 bf16 (4 VGPR)
typedef __attribute__((ext_vector_type(4))) float floatx4;    // MFMA C/D
typedef __attribute__((ext_vector_type(4))) unsigned int uint4v;
typedef __attribute__((ext_vector_type(4))) float float4v;

static __device__ __forceinline__ ushort_t f2bf(float f) {
    unsigned int u = __builtin_bit_cast(unsigned int, f);
    u += 0x7FFFu + ((u >> 16) & 1u);   // RNE
    return (ushort_t)(u >> 16);
}
static __device__ __forceinline__ float bf2f(ushort_t h) {
    unsigned int u = ((unsigned int)h) << 16;
    return __builtin_bit_cast(float, u);
}
static __device__ __forceinline__ float sigmoidf_(float x) {
    return 1.0f / (1.0f + __expf(-x));
}
static __device__ __forceinline__ floatx4 mfma16(short8 a, short8 b, floatx4 c) {
    return __builtin_amdgcn_mfma_f32_16x16x32_bf16(a, b, c, 0, 0, 0);
}

// ---------------------------------------------------------------------------
// Kernel W: fragment-ordered bf16 weights.
//   wt[mat][idx], idx = nt*2048 + kc*512 + lane*8 + e
//   value = W[k][n] with n = nt*16 + (lane&15), k = kc*32 + (lane>>4)*8 + e.
// A B-fragment load is then ONE coalesced 1 KB wave transaction.
// ---------------------------------------------------------------------------
__global__ __launch_bounds__(256) void wconv6(
    const float* __restrict__ Wl, const float* __restrict__ Wr,
    const float* __restrict__ Wgl, const float* __restrict__ Wgr,
    const float* __restrict__ Wg, const float* __restrict__ Wo,
    ushort_t* __restrict__ wt)
{
    __shared__ float tile[128 * 132];     // tile[k][n], +4 pad
    const float* Ws[6] = {Wl, Wr, Wgl, Wgr, Wg, Wo};
    const float* W = Ws[blockIdx.x];
    ushort_t* dst = wt + blockIdx.x * 16384;
    const int t = threadIdx.x;
    for (int e = t; e < 16384; e += 256)
        tile[(e >> 7) * 132 + (e & 127)] = W[e];
    __syncthreads();
    for (int idx = t; idx < 16384; idx += 256) {
        int e = idx & 7, lane = (idx >> 3) & 63, kc = (idx >> 9) & 3, nt = idx >> 11;
        int n = nt * 16 + (lane & 15);
        int k = kc * 32 + (lane >> 4) * 8 + e;
        dst[idx] = f2bf(tile[k * 132 + n]);
    }
}

// ---------------------------------------------------------------------------
// Kernel A (v5): per 128 rows of [NN, C]: LN -> bf16, 5 projections via MFMA.
// Each wave owns 32 rows (2 row-groups of 16): every weight-fragment load
// feeds 4 MFMAs (2 row-groups x A/B), halving L2 weight traffic vs 64-row
// blocks. Single 34.8 KB LDS region phase-aliased: x (LN out, read only by
// the wave that wrote it) then st (transpose staging), alias bracketed by
// __syncthreads after afrag register loads.
// ---------------------------------------------------------------------------
__global__ __launch_bounds__(256) void proj_kernel(
    const float* __restrict__ act, const float* __restrict__ mask,
    const float* __restrict__ ln_g, const float* __restrict__ ln_b,
    const float* __restrict__ bl, const float* __restrict__ bgl,
    const float* __restrict__ br, const float* __restrict__ bgr,
    const float* __restrict__ bg,
    const ushort_t* __restrict__ wt,
    ushort_t* __restrict__ leftT, ushort_t* __restrict__ rightT,
    ushort_t* __restrict__ gateO)
{
    __shared__ __align__(16) ushort_t smem[128 * 136];   // 34816 B, aliased
    __shared__ float mask_lds[128];
    ushort_t* x_lds = smem;        // phase 1: [row][136] bf16 LN(act)
    ushort_t* st_lds = smem;       // phase 2+: [c][136] or [row][136]

    const int t = threadIdx.x;
    const int row0 = blockIdx.x * 128;
    const int i = row0 / NDIM;     // fixed per block (128 | 384)
    const int k0 = row0 % NDIM;
    const int wave = t >> 6;
    const int lane = t & 63;

    if (t < 128) mask_lds[t] = mask[row0 + t];

    // LayerNorm straight from global: wave w owns rows w*32..w*32+31.
    {
        const float g1 = ln_g[lane], g2 = ln_g[lane + 64];
        const float b1 = ln_b[lane], b2 = ln_b[lane + 64];
#pragma unroll
        for (int rr = 0; rr < 32; ++rr) {
            int r = wave * 32 + rr;
            const float* ar = act + (size_t)(row0 + r) * CDIM;
            float x1 = ar[lane], x2 = ar[lane + 64];
            float s = x1 + x2, s2 = x1 * x1 + x2 * x2;
#pragma unroll
            for (int off = 32; off >= 1; off >>= 1) {
                s  += __shfl_xor(s, off);
                s2 += __shfl_xor(s2, off);
            }
            float mu = s * (1.0f / 128.0f);
            float var = s2 * (1.0f / 128.0f) - mu * mu;
            float rstd = rsqrtf(fmaxf(var, 0.0f) + EPS);
            x_lds[r * 136 + lane]      = f2bf((x1 - mu) * rstd * g1 + b1);
            x_lds[r * 136 + lane + 64] = f2bf((x2 - mu) * rstd * g2 + b2);
        }
    }

    // A fragments from OWN wave's rows (same-wave LDS dep, compiler-ordered).
    short8 afrag[2][4];
    {
        int kb = (lane >> 4) * 8;
#pragma unroll
        for (int rg = 0; rg < 2; ++rg) {
            int r = wave * 32 + rg * 16 + (lane & 15);
#pragma unroll
            for (int kc = 0; kc < 4; ++kc)
                afrag[rg][kc] = *(const short8*)&x_lds[r * 136 + kc * 32 + kb];
        }
    }
    __syncthreads();   // afrag in regs everywhere; x region becomes st.

    const int n16 = lane & 15;
    const int rsub = (lane >> 4) << 2;   // 0,4,8,12

    // projection pair -> masked * (pA+bA) * sigmoid(pB+bB) -> st_lds[c][row]
    auto do_pair = [&](const ushort_t* WtA, const ushort_t* WtB,
                       const float* __restrict__ bA, const float* __restrict__ bB) {
#pragma unroll
        for (int nt = 0; nt < 8; ++nt) {
            const int n = nt * 16 + n16;
            floatx4 accA[2], accB[2];
#pragma unroll
            for (int rg = 0; rg < 2; ++rg) {
                accA[rg] = (floatx4){0.f, 0.f, 0.f, 0.f};
                accB[rg] = (floatx4){0.f, 0.f, 0.f, 0.f};
            }
#pragma unroll
            for (int kc = 0; kc < 4; ++kc) {
                short8 fbA = *(const short8*)&WtA[nt * 2048 + kc * 512 + lane * 8];
                short8 fbB = *(const short8*)&WtB[nt * 2048 + kc * 512 + lane * 8];
                accA[0] = mfma16(afrag[0][kc], fbA, accA[0]);
                accA[1] = mfma16(afrag[1][kc], fbA, accA[1]);
                accB[0] = mfma16(afrag[0][kc], fbB, accB[0]);
                accB[1] = mfma16(afrag[1][kc], fbB, accB[1]);
            }
            const float biasA = bA[n], biasB = bB[n];
#pragma unroll
            for (int rg = 0; rg < 2; ++rg) {
#pragma unroll
                for (int reg = 0; reg < 4; ++reg) {
                    int rloc = wave * 32 + rg * 16 + rsub + reg;
                    float v = mask_lds[rloc] * (accA[rg][reg] + biasA)
                                             * sigmoidf_(accB[rg][reg] + biasB);
                    st_lds[n * 136 + rloc] = f2bf(v);
                }
            }
        }
    };

    // flush st_lds[c][row] -> dst[c*NN + i*384 + k0 + row], coalesced
    auto flush_ck = [&](ushort_t* __restrict__ dst) {
        __syncthreads();
        int cc = t >> 1, rh = (t & 1) * 64;
        const uint4v* s = (const uint4v*)&st_lds[cc * 136 + rh];
        uint4v* d = (uint4v*)&dst[(size_t)cc * NN + i * NDIM + k0 + rh];
#pragma unroll
        for (int q = 0; q < 8; ++q) d[q] = s[q];
        __syncthreads();
    };

    do_pair(wt + 0 * 16384, wt + 2 * 16384, bl, bgl);   // Wl, Wgl
    flush_ck(leftT);
    do_pair(wt + 1 * 16384, wt + 3 * 16384, br, bgr);   // Wr, Wgr
    flush_ck(rightT);

    // gate = sigmoid(x@Wg + bg), stored [row][c]
    {
        const ushort_t* WtG = wt + 4 * 16384;
#pragma unroll
        for (int nt = 0; nt < 8; ++nt) {
            const int n = nt * 16 + n16;
            floatx4 acc[2];
            acc[0] = (floatx4){0.f, 0.f, 0.f, 0.f};
            acc[1] = (floatx4){0.f, 0.f, 0.f, 0.f};
#pragma unroll
            for (int kc = 0; kc < 4; ++kc) {
                short8 fb = *(const short8*)&WtG[nt * 2048 + kc * 512 + lane * 8];
                acc[0] = mfma16(afrag[0][kc], fb, acc[0]);
                acc[1] = mfma16(afrag[1][kc], fb, acc[1]);
            }
            const float bias = bg[n];
#pragma unroll
            for (int rg = 0; rg < 2; ++rg) {
#pragma unroll
                for (int reg = 0; reg < 4; ++reg) {
                    int rloc = wave * 32 + rg * 16 + rsub + reg;
                    st_lds[rloc * 136 + n] = f2bf(sigmoidf_(acc[rg][reg] + bias));
                }
            }
        }
        __syncthreads();
        int r = t >> 1, ch = (t & 1) * 64;
        const uint4v* s = (const uint4v*)&st_lds[r * 136 + ch];
        uint4v* d = (uint4v*)&gateO[(size_t)(row0 + r) * CDIM + ch];
#pragma unroll
        for (int q = 0; q < 8; ++q) d[q] = s[q];
    }
}

// ---------------------------------------------------------------------------
// Kernel B: per-channel triangle GEMM. tri[c][i][j] = sum_k L[c][i][k]*R[c][j][k]
// (byte-identical to round 4)
// ---------------------------------------------------------------------------
__global__ __launch_bounds__(256) void tri_kernel(
    const ushort_t* __restrict__ leftT, const ushort_t* __restrict__ rightT,
    ushort_t* __restrict__ tri)
{
    __shared__ ushort_t Lt[128 * 72];
    __shared__ ushort_t Rt[128 * 72];
    const int t = threadIdx.x;
    const int bid0 = blockIdx.y * 9 + blockIdx.x;     // 0..1151
    const int bid = (bid0 % 8) * 144 + (bid0 / 8);    // XCD-chunked, bijective
    const int c = bid / 9;
    const int tile9 = bid % 9;
    const int it = tile9 / 3, jt = tile9 % 3;
    const int i0 = it * 128, j0 = jt * 128;
    const int wave = t >> 6, lane = t & 63;
    const int wi = (wave >> 1) * 64, wj = (wave & 1) * 64;

    const ushort_t* Lb = leftT + (size_t)c * NN + (size_t)i0 * NDIM;
    const ushort_t* Rb = rightT + (size_t)c * NN + (size_t)j0 * NDIM;

    floatx4 acc[4][4];
#pragma unroll
    for (int a = 0; a < 4; ++a)
#pragma unroll
        for (int b = 0; b < 4; ++b) acc[a][b] = (floatx4){0.f, 0.f, 0.f, 0.f};

    const int sr = t >> 1, skh = (t & 1) * 32;
    for (int kb = 0; kb < NDIM; kb += 64) {
        const uint4v* sL = (const uint4v*)&Lb[sr * NDIM + kb + skh];
        const uint4v* sR = (const uint4v*)&Rb[sr * NDIM + kb + skh];
        uint4v* dL = (uint4v*)&Lt[sr * 72 + skh];
        uint4v* dR = (uint4v*)&Rt[sr * 72 + skh];
#pragma unroll
        for (int q = 0; q < 4; ++q) { dL[q] = sL[q]; dR[q] = sR[q]; }
        __syncthreads();
#pragma unroll
        for (int kc = 0; kc < 2; ++kc) {
            const int kk = kc * 32 + (lane >> 4) * 8;
            short8 af[4], bfr[4];
#pragma unroll
            for (int mt = 0; mt < 4; ++mt)
                af[mt] = *(const short8*)&Lt[(wi + mt * 16 + (lane & 15)) * 72 + kk];
#pragma unroll
            for (int nt = 0; nt < 4; ++nt)
                bfr[nt] = *(const short8*)&Rt[(wj + nt * 16 + (lane & 15)) * 72 + kk];
#pragma unroll
            for (int mt = 0; mt < 4; ++mt)
#pragma unroll
                for (int nt = 0; nt < 4; ++nt)
                    acc[mt][nt] = mfma16(af[mt], bfr[nt], acc[mt][nt]);
        }
        __syncthreads();
    }

    ushort_t* outb = tri + (size_t)c * NN;
#pragma unroll
    for (int mt = 0; mt < 4; ++mt) {
#pragma unroll
        for (int reg = 0; reg < 4; ++reg) {
            int ii = i0 + wi + mt * 16 + (lane >> 4) * 4 + reg;
#pragma unroll
            for (int nt = 0; nt < 4; ++nt) {
                int jj = j0 + wj + nt * 16 + (lane & 15);
                outb[(size_t)ii * NDIM + jj] = f2bf(acc[mt][nt][reg]);
            }
        }
    }
}

// ---------------------------------------------------------------------------
// Kernel C: out = (LN2(tri_bf16) @ Wo + bo) * gate
// (byte-identical to round 4)
// ---------------------------------------------------------------------------
__global__ __launch_bounds__(256) void out_kernel(
    const ushort_t* __restrict__ tri, const float* __restrict__ cg,
    const float* __restrict__ cb,
    const ushort_t* __restrict__ wtO, const float* __restrict__ bo,
    const ushort_t* __restrict__ gate, float* __restrict__ outp)
{
    __shared__ __align__(16) float t_lds[64 * 132];  // [j][c] pad 132; reused
                                                     // as output staging
    __shared__ ushort_t x_lds[64][136];
    const int t = threadIdx.x;
    const int row0 = blockIdx.x * 64;
    const int i = row0 / NDIM, j0 = row0 % NDIM;
    const int wave = t >> 6, lane = t & 63;

    // transpose: tri_bf16[c][i][j0+jh..+32] -> t_lds[j][c] (f32)
    {
        const int c = t >> 1, jh = (t & 1) * 32;
        const ushort_t* src = tri + (size_t)c * NN + (size_t)i * NDIM + j0 + jh;
#pragma unroll
        for (int q = 0; q < 4; ++q) {
            short8 v8 = *(const short8*)(src + q * 8);
#pragma unroll
            for (int e = 0; e < 8; ++e)
                t_lds[(jh + q * 8 + e) * 132 + c] = bf2f((ushort_t)v8[e]);
        }
    }
    __syncthreads();

    {
        const float g1 = cg[lane], g2 = cg[lane + 64];
        const float b1 = cb[lane], b2 = cb[lane + 64];
#pragma unroll
        for (int rr = 0; rr < 16; ++rr) {
            int r = wave * 16 + rr;
            float x1 = t_lds[r * 132 + lane], x2 = t_lds[r * 132 + lane + 64];
            float s = x1 + x2, s2 = x1 * x1 + x2 * x2;
#pragma unroll
            for (int off = 32; off >= 1; off >>= 1) {
                s  += __shfl_xor(s, off);
                s2 += __shfl_xor(s2, off);
            }
            float mu = s * (1.0f / 128.0f);
            float var = s2 * (1.0f / 128.0f) - mu * mu;
            float rstd = rsqrtf(fmaxf(var, 0.0f) + EPS);
            x_lds[r][lane]      = f2bf((x1 - mu) * rstd * g1 + b1);
            x_lds[r][lane + 64] = f2bf((x2 - mu) * rstd * g2 + b2);
        }
    }
    __syncthreads();
    // t_lds (as LN input) dead from here; reused below as output staging.

    short8 afrag[4];
    {
        int r = wave * 16 + (lane & 15);
        int kb = (lane >> 4) * 8;
#pragma unroll
        for (int kc = 0; kc < 4; ++kc)
            afrag[kc] = *(const short8*)&x_lds[r][kc * 32 + kb];
    }

    const int n16 = lane & 15;
#pragma unroll
    for (int nt = 0; nt < 8; ++nt) {
        const int n = nt * 16 + n16;
        floatx4 acc = {0.f, 0.f, 0.f, 0.f};
#pragma unroll
        for (int kc = 0; kc < 4; ++kc) {
            short8 fb = *(const short8*)&wtO[nt * 2048 + kc * 512 + lane * 8];
            acc = mfma16(afrag[kc], fb, acc);
        }
        const float bias = bo[n];
#pragma unroll
        for (int reg = 0; reg < 4; ++reg) {
            int rloc = wave * 16 + (lane >> 4) * 4 + reg;
            t_lds[rloc * 132 + n] = acc[reg] + bias;
        }
    }
    __syncthreads();

    // coalesced gated store: thread covers [r][c0..c0+31]
    {
        const int r = t >> 2, c0 = (t & 3) * 32;
        const uint4v* gv = (const uint4v*)&gate[(size_t)(row0 + r) * CDIM + c0];
        float4v* dst = (float4v*)&outp[(size_t)(row0 + r) * CDIM + c0];
#pragma unroll
        for (int q = 0; q < 4; ++q) {
            uint4v g8 = gv[q];
            float4v a = *(const float4v*)&t_lds[r * 132 + c0 + q * 8];
            float4v b = *(const float4v*)&t_lds[r * 132 + c0 + q * 8 + 4];
            a.x *= bf2f((ushort_t)(g8.x & 0xffff));
            a.y *= bf2f((ushort_t)(g8.x >> 16));
            a.z *= bf2f((ushort_t)(g8.y & 0xffff));
            a.w *= bf2f((ushort_t)(g8.y >> 16));
            b.x *= bf2f((ushort_t)(g8.z & 0xffff));
            b.y *= bf2f((ushort_t)(g8.z >> 16));
            b.z *= bf2f((ushort_t)(g8.w & 0xffff));
            b.w *= bf2f((ushort_t)(g8.w >> 16));
            dst[q * 2 + 0] = a;
            dst[q * 2 + 1] = b;
        }
    }
}

// ---------------------------------------------------------------------------
extern "C" void kernel_launch(void* const* d_in, const int* in_sizes, int n_in,
                              void* d_out, int out_size, void* d_ws, size_t ws_size,
                              hipStream_t stream)
{
    const float* act  = (const float*)d_in[0];
    const float* mask = (const float*)d_in[1];
    const float* ln_g = (const float*)d_in[2];
    const float* ln_b = (const float*)d_in[3];
    const float* Wl   = (const float*)d_in[4];
    const float* bl   = (const float*)d_in[5];
    const float* Wr   = (const float*)d_in[6];
    const float* br   = (const float*)d_in[7];
    const float* Wgl  = (const float*)d_in[8];
    const float* bgl  = (const float*)d_in[9];
    const float* Wgr  = (const float*)d_in[10];
    const float* bgr  = (const float*)d_in[11];
    const float* cg   = (const float*)d_in[12];
    const float* cb   = (const float*)d_in[13];
    const float* Wo   = (const float*)d_in[14];
    const float* bo   = (const float*)d_in[15];
    const float* Wg   = (const float*)d_in[16];
    const float* bg   = (const float*)d_in[17];
    float* outp = (float*)d_out;

    // workspace (ushorts): leftT | rightT | gate (CDIM*NN each) | wt 6*16384 |
    //                      tri bf16 CDIM*NN   => ~151 MB total
    ushort_t* ws16   = (ushort_t*)d_ws;
    ushort_t* leftT  = ws16;
    ushort_t* rightT = ws16 + (size_t)CDIM * NN;
    ushort_t* gate   = ws16 + (size_t)2 * CDIM * NN;
    ushort_t* wt     = ws16 + (size_t)3 * CDIM * NN;
    ushort_t* triB   = ws16 + (size_t)3 * CDIM * NN + 6 * 16384;

    wconv6<<<6, 256, 0, stream>>>(Wl, Wr, Wgl, Wgr, Wg, Wo, wt);
    proj_kernel<<<NN / 128, 256, 0, stream>>>(act, mask, ln_g, ln_b,
                                              bl, bgl, br, bgr, bg,
                                              wt, leftT, rightT, gate);
    tri_kernel<<<dim3(9, 128), 256, 0, stream>>>(leftT, rightT, triB);
    out_kernel<<<NN / 64, 256, 0, stream>>>(triB, cg, cb, wt + 5 * 16384, bo,
                                            gate, outp);
}

// Round 6
// 335.701 us; speedup vs baseline: 1.1249x; 1.1249x over previous
//
#include <hip/hip_runtime.h>

#define EPS 1e-5f
#define NDIM 384
#define CDIM 128
#define NN (NDIM * NDIM)   // 147456

typedef unsigned short ushort_t;
typedef __attribute__((ext_vector_type(8))) short short8;     // 8 bf16 (4 VGPR)
typedef __attribute__((ext_vector_type(4))) float floatx4;    // MFMA C/D
typedef __attribute__((ext_vector_type(4))) unsigned int uint4v;
typedef __attribute__((ext_vector_type(4))) float float4v;

static __device__ __forceinline__ ushort_t f2bf(float f) {
    unsigned int u = __builtin_bit_cast(unsigned int, f);
    u += 0x7FFFu + ((u >> 16) & 1u);   // RNE
    return (ushort_t)(u >> 16);
}
static __device__ __forceinline__ float bf2f(ushort_t h) {
    unsigned int u = ((unsigned int)h) << 16;
    return __builtin_bit_cast(float, u);
}
static __device__ __forceinline__ float sigmoidf_(float x) {
    return 1.0f / (1.0f + __expf(-x));
}
static __device__ __forceinline__ floatx4 mfma16(short8 a, short8 b, floatx4 c) {
    return __builtin_amdgcn_mfma_f32_16x16x32_bf16(a, b, c, 0, 0, 0);
}
// async global->LDS, 16B per lane; LDS dest wave-uniform base + lane*16
static __device__ __forceinline__ void gload16(const ushort_t* g, ushort_t* l) {
    __builtin_amdgcn_global_load_lds(
        (const __attribute__((address_space(1))) void*)g,
        (__attribute__((address_space(3))) void*)l, 16, 0, 0);
}

// ---------------------------------------------------------------------------
// Kernel W: fragment-ordered bf16 weights.
//   wt[mat][idx], idx = nt*2048 + kc*512 + lane*8 + e
//   value = W[k][n] with n = nt*16 + (lane&15), k = kc*32 + (lane>>4)*8 + e.
// ---------------------------------------------------------------------------
__global__ __launch_bounds__(256) void wconv6(
    const float* __restrict__ Wl, const float* __restrict__ Wr,
    const float* __restrict__ Wgl, const float* __restrict__ Wgr,
    const float* __restrict__ Wg, const float* __restrict__ Wo,
    ushort_t* __restrict__ wt)
{
    __shared__ float tile[128 * 132];     // tile[k][n], +4 pad
    const float* Ws[6] = {Wl, Wr, Wgl, Wgr, Wg, Wo};
    const float* W = Ws[blockIdx.x];
    ushort_t* dst = wt + blockIdx.x * 16384;
    const int t = threadIdx.x;
    for (int e = t; e < 16384; e += 256)
        tile[(e >> 7) * 132 + (e & 127)] = W[e];
    __syncthreads();
    for (int idx = t; idx < 16384; idx += 256) {
        int e = idx & 7, lane = (idx >> 3) & 63, kc = (idx >> 9) & 3, nt = idx >> 11;
        int n = nt * 16 + (lane & 15);
        int k = kc * 32 + (lane >> 4) * 8 + e;
        dst[idx] = f2bf(tile[k * 132 + n]);
    }
}

// ---------------------------------------------------------------------------
// Kernel A: per 64 rows of [NN, C]: LN -> bf16, then 5 projections via MFMA.
// (byte-identical to round 4 — known 114 us)
// ---------------------------------------------------------------------------
__global__ __launch_bounds__(256) void proj_kernel(
    const float* __restrict__ act, const float* __restrict__ mask,
    const float* __restrict__ ln_g, const float* __restrict__ ln_b,
    const float* __restrict__ bl, const float* __restrict__ bgl,
    const float* __restrict__ br, const float* __restrict__ bgr,
    const float* __restrict__ bg,
    const ushort_t* __restrict__ wt,
    ushort_t* __restrict__ leftT, ushort_t* __restrict__ rightT,
    ushort_t* __restrict__ gateO)
{
    __shared__ ushort_t x_lds[64][136];                  // bf16 LN(act), +8 pad
    __shared__ __align__(16) ushort_t st_lds[128 * 72];  // staging (separate)
    __shared__ float mask_lds[64];

    const int t = threadIdx.x;
    const int row0 = blockIdx.x * 64;
    const int i = row0 / NDIM;     // fixed per block (64 | 384)
    const int k0 = row0 % NDIM;
    const int wave = t >> 6;
    const int lane = t & 63;

    if (t < 64) mask_lds[t] = mask[row0 + t];

    // LayerNorm straight from global: wave w owns rows w*16..w*16+15.
    {
        const float g1 = ln_g[lane], g2 = ln_g[lane + 64];
        const float b1 = ln_b[lane], b2 = ln_b[lane + 64];
#pragma unroll
        for (int rr = 0; rr < 16; ++rr) {
            int r = wave * 16 + rr;
            const float* ar = act + (size_t)(row0 + r) * CDIM;
            float x1 = ar[lane], x2 = ar[lane + 64];
            float s = x1 + x2, s2 = x1 * x1 + x2 * x2;
#pragma unroll
            for (int off = 32; off >= 1; off >>= 1) {
                s  += __shfl_xor(s, off);
                s2 += __shfl_xor(s2, off);
            }
            float mu = s * (1.0f / 128.0f);
            float var = s2 * (1.0f / 128.0f) - mu * mu;
            float rstd = rsqrtf(fmaxf(var, 0.0f) + EPS);
            x_lds[r][lane]      = f2bf((x1 - mu) * rstd * g1 + b1);
            x_lds[r][lane + 64] = f2bf((x2 - mu) * rstd * g2 + b2);
        }
    }
    __syncthreads();

    // A fragments: row = wave*16 + (lane&15), k = kc*32 + (lane>>4)*8 + e
    short8 afrag[4];
    {
        int r = wave * 16 + (lane & 15);
        int kb = (lane >> 4) * 8;
#pragma unroll
        for (int kc = 0; kc < 4; ++kc)
            afrag[kc] = *(const short8*)&x_lds[r][kc * 32 + kb];
    }

    const int n16 = lane & 15;

    // projection pair -> masked * (pA+bA) * sigmoid(pB+bB) -> st_lds[c][row]
    auto do_pair = [&](const ushort_t* WtA, const ushort_t* WtB,
                       const float* __restrict__ bA, const float* __restrict__ bB) {
#pragma unroll
        for (int nt = 0; nt < 8; ++nt) {
            const int n = nt * 16 + n16;
            floatx4 accA = {0.f, 0.f, 0.f, 0.f};
            floatx4 accB = {0.f, 0.f, 0.f, 0.f};
#pragma unroll
            for (int kc = 0; kc < 4; ++kc) {
                short8 fbA = *(const short8*)&WtA[nt * 2048 + kc * 512 + lane * 8];
                accA = mfma16(afrag[kc], fbA, accA);
                short8 fbB = *(const short8*)&WtB[nt * 2048 + kc * 512 + lane * 8];
                accB = mfma16(afrag[kc], fbB, accB);
            }
            const float biasA = bA[n], biasB = bB[n];
#pragma unroll
            for (int reg = 0; reg < 4; ++reg) {
                int rloc = wave * 16 + (lane >> 4) * 4 + reg;
                float v = mask_lds[rloc] * (accA[reg] + biasA)
                                         * sigmoidf_(accB[reg] + biasB);
                st_lds[n * 72 + rloc] = f2bf(v);
            }
        }
    };

    // flush st_lds[c][row] -> dst[c*NN + i*384 + k0 + row], coalesced
    auto flush_ck = [&](ushort_t* __restrict__ dst) {
        __syncthreads();
        int cc = t >> 1, kh = (t & 1) * 32;
        const uint4v* s = (const uint4v*)&st_lds[cc * 72 + kh];
        uint4v* d = (uint4v*)&dst[(size_t)cc * NN + i * NDIM + k0 + kh];
#pragma unroll
        for (int q = 0; q < 4; ++q) d[q] = s[q];
        __syncthreads();
    };

    do_pair(wt + 0 * 16384, wt + 2 * 16384, bl, bgl);   // Wl, Wgl
    flush_ck(leftT);
    do_pair(wt + 1 * 16384, wt + 3 * 16384, br, bgr);   // Wr, Wgr
    flush_ck(rightT);

    // gate = sigmoid(x@Wg + bg), stored [row][c]
    {
        const ushort_t* WtG = wt + 4 * 16384;
#pragma unroll
        for (int nt = 0; nt < 8; ++nt) {
            const int n = nt * 16 + n16;
            floatx4 acc = {0.f, 0.f, 0.f, 0.f};
#pragma unroll
            for (int kc = 0; kc < 4; ++kc) {
                short8 fb = *(const short8*)&WtG[nt * 2048 + kc * 512 + lane * 8];
                acc = mfma16(afrag[kc], fb, acc);
            }
            const float bias = bg[n];
#pragma unroll
            for (int reg = 0; reg < 4; ++reg) {
                int rloc = wave * 16 + (lane >> 4) * 4 + reg;
                st_lds[rloc * 128 + n] = f2bf(sigmoidf_(acc[reg] + bias));
            }
        }
        __syncthreads();
        int r = t >> 2, c0 = (t & 3) * 32;
        const uint4v* s = (const uint4v*)&st_lds[r * 128 + c0];
        uint4v* d = (uint4v*)&gateO[(size_t)(row0 + r) * CDIM + c0];
#pragma unroll
        for (int q = 0; q < 4; ++q) d[q] = s[q];
    }
}

// ---------------------------------------------------------------------------
// Kernel B (v6): per-channel triangle GEMM via global_load_lds staging.
// LDS tiles are LINEAR [128][64] bf16; bank conflicts on the b128 fragment
// reads are avoided with a both-sides XOR swizzle (rule 21):
//   physical 16B-granule g_phys = g_log ^ (row&7)
// realized by pre-swizzling the per-lane GLOBAL source address (gload_lds
// writes lane l at ldsbase + l*16: row = r0+(l>>3), g_phys = l&7, so lane l
// fetches logical granule (l&7)^(l>>3) of its row) and XORing the ds_read
// address with (lane&7) (row&7 == lane&7 for all fragment rows).
// ---------------------------------------------------------------------------
__global__ __launch_bounds__(256) void tri_kernel(
    const ushort_t* __restrict__ leftT, const ushort_t* __restrict__ rightT,
    ushort_t* __restrict__ tri)
{
    __shared__ __align__(16) ushort_t Lt[128 * 64];   // 16 KB, linear+swizzled
    __shared__ __align__(16) ushort_t Rt[128 * 64];   // 16 KB
    const int t = threadIdx.x;
    const int bid0 = blockIdx.y * 9 + blockIdx.x;     // 0..1151
    const int bid = (bid0 % 8) * 144 + (bid0 / 8);    // XCD-chunked, bijective
    const int c = bid / 9;
    const int tile9 = bid % 9;
    const int it = tile9 / 3, jt = tile9 % 3;
    const int i0 = it * 128, j0 = jt * 128;
    const int wave = t >> 6, lane = t & 63;
    const int wi = (wave >> 1) * 64, wj = (wave & 1) * 64;

    const ushort_t* Lb = leftT + (size_t)c * NN + (size_t)i0 * NDIM;
    const ushort_t* Rb = rightT + (size_t)c * NN + (size_t)j0 * NDIM;

    // staging source offsets (per lane): row r0+(lane>>3), granule (lane&7)^(lane>>3)
    const int srow = lane >> 3;                         // 0..7
    const int ssw  = ((lane & 7) ^ (lane >> 3)) * 8;    // ushort offset in row

    floatx4 acc[4][4];
#pragma unroll
    for (int a = 0; a < 4; ++a)
#pragma unroll
        for (int b = 0; b < 4; ++b) acc[a][b] = (floatx4){0.f, 0.f, 0.f, 0.f};

    for (int kb = 0; kb < NDIM; kb += 64) {
        // stage: each wave covers rows wave*32..wave*32+31 of L and R
#pragma unroll
        for (int q = 0; q < 4; ++q) {
            const int r0 = wave * 32 + q * 8;
            gload16(Lb + (size_t)(r0 + srow) * NDIM + kb + ssw, &Lt[r0 * 64]);
            gload16(Rb + (size_t)(r0 + srow) * NDIM + kb + ssw, &Rt[r0 * 64]);
        }
        __syncthreads();   // vmcnt drain -> LDS tiles ready
#pragma unroll
        for (int kc = 0; kc < 2; ++kc) {
            // logical granule kc*4+(lane>>4); row&7 == lane&7 for all rows
            const int gp = ((kc * 4 + (lane >> 4)) ^ (lane & 7)) * 8;
            short8 af[4], bfr[4];
#pragma unroll
            for (int mt = 0; mt < 4; ++mt)
                af[mt] = *(const short8*)&Lt[(wi + mt * 16 + (lane & 15)) * 64 + gp];
#pragma unroll
            for (int nt = 0; nt < 4; ++nt)
                bfr[nt] = *(const short8*)&Rt[(wj + nt * 16 + (lane & 15)) * 64 + gp];
#pragma unroll
            for (int mt = 0; mt < 4; ++mt)
#pragma unroll
                for (int nt = 0; nt < 4; ++nt)
                    acc[mt][nt] = mfma16(af[mt], bfr[nt], acc[mt][nt]);
        }
        __syncthreads();   // readers done before next stage overwrites
    }

    ushort_t* outb = tri + (size_t)c * NN;
#pragma unroll
    for (int mt = 0; mt < 4; ++mt) {
#pragma unroll
        for (int reg = 0; reg < 4; ++reg) {
            int ii = i0 + wi + mt * 16 + (lane >> 4) * 4 + reg;
#pragma unroll
            for (int nt = 0; nt < 4; ++nt) {
                int jj = j0 + wj + nt * 16 + (lane & 15);
                outb[(size_t)ii * NDIM + jj] = f2bf(acc[mt][nt][reg]);
            }
        }
    }
}

// ---------------------------------------------------------------------------
// Kernel C: out = (LN2(tri_bf16) @ Wo + bo) * gate
// (byte-identical to round 4)
// ---------------------------------------------------------------------------
__global__ __launch_bounds__(256) void out_kernel(
    const ushort_t* __restrict__ tri, const float* __restrict__ cg,
    const float* __restrict__ cb,
    const ushort_t* __restrict__ wtO, const float* __restrict__ bo,
    const ushort_t* __restrict__ gate, float* __restrict__ outp)
{
    __shared__ __align__(16) float t_lds[64 * 132];  // [j][c] pad 132; reused
                                                     // as output staging
    __shared__ ushort_t x_lds[64][136];
    const int t = threadIdx.x;
    const int row0 = blockIdx.x * 64;
    const int i = row0 / NDIM, j0 = row0 % NDIM;
    const int wave = t >> 6, lane = t & 63;

    // transpose: tri_bf16[c][i][j0+jh..+32] -> t_lds[j][c] (f32)
    {
        const int c = t >> 1, jh = (t & 1) * 32;
        const ushort_t* src = tri + (size_t)c * NN + (size_t)i * NDIM + j0 + jh;
#pragma unroll
        for (int q = 0; q < 4; ++q) {
            short8 v8 = *(const short8*)(src + q * 8);
#pragma unroll
            for (int e = 0; e < 8; ++e)
                t_lds[(jh + q * 8 + e) * 132 + c] = bf2f((ushort_t)v8[e]);
        }
    }
    __syncthreads();

    {
        const float g1 = cg[lane], g2 = cg[lane + 64];
        const float b1 = cb[lane], b2 = cb[lane + 64];
#pragma unroll
        for (int rr = 0; rr < 16; ++rr) {
            int r = wave * 16 + rr;
            float x1 = t_lds[r * 132 + lane], x2 = t_lds[r * 132 + lane + 64];
            float s = x1 + x2, s2 = x1 * x1 + x2 * x2;
#pragma unroll
            for (int off = 32; off >= 1; off >>= 1) {
                s  += __shfl_xor(s, off);
                s2 += __shfl_xor(s2, off);
            }
            float mu = s * (1.0f / 128.0f);
            float var = s2 * (1.0f / 128.0f) - mu * mu;
            float rstd = rsqrtf(fmaxf(var, 0.0f) + EPS);
            x_lds[r][lane]      = f2bf((x1 - mu) * rstd * g1 + b1);
            x_lds[r][lane + 64] = f2bf((x2 - mu) * rstd * g2 + b2);
        }
    }
    __syncthreads();
    // t_lds (as LN input) dead from here; reused below as output staging.

    short8 afrag[4];
    {
        int r = wave * 16 + (lane & 15);
        int kb = (lane >> 4) * 8;
#pragma unroll
        for (int kc = 0; kc < 4; ++kc)
            afrag[kc] = *(const short8*)&x_lds[r][kc * 32 + kb];
    }

    const int n16 = lane & 15;
#pragma unroll
    for (int nt = 0; nt < 8; ++nt) {
        const int n = nt * 16 + n16;
        floatx4 acc = {0.f, 0.f, 0.f, 0.f};
#pragma unroll
        for (int kc = 0; kc < 4; ++kc) {
            short8 fb = *(const short8*)&wtO[nt * 2048 + kc * 512 + lane * 8];
            acc = mfma16(afrag[kc], fb, acc);
        }
        const float bias = bo[n];
#pragma unroll
        for (int reg = 0; reg < 4; ++reg) {
            int rloc = wave * 16 + (lane >> 4) * 4 + reg;
            t_lds[rloc * 132 + n] = acc[reg] + bias;
        }
    }
    __syncthreads();

    // coalesced gated store: thread covers [r][c0..c0+31]
    {
        const int r = t >> 2, c0 = (t & 3) * 32;
        const uint4v* gv = (const uint4v*)&gate[(size_t)(row0 + r) * CDIM + c0];
        float4v* dst = (float4v*)&outp[(size_t)(row0 + r) * CDIM + c0];
#pragma unroll
        for (int q = 0; q < 4; ++q) {
            uint4v g8 = gv[q];
            float4v a = *(const float4v*)&t_lds[r * 132 + c0 + q * 8];
            float4v b = *(const float4v*)&t_lds[r * 132 + c0 + q * 8 + 4];
            a.x *= bf2f((ushort_t)(g8.x & 0xffff));
            a.y *= bf2f((ushort_t)(g8.x >> 16));
            a.z *= bf2f((ushort_t)(g8.y & 0xffff));
            a.w *= bf2f((ushort_t)(g8.y >> 16));
            b.x *= bf2f((ushort_t)(g8.z & 0xffff));
            b.y *= bf2f((ushort_t)(g8.z >> 16));
            b.z *= bf2f((ushort_t)(g8.w & 0xffff));
            b.w *= bf2f((ushort_t)(g8.w >> 16));
            dst[q * 2 + 0] = a;
            dst[q * 2 + 1] = b;
        }
    }
}

// ---------------------------------------------------------------------------
extern "C" void kernel_launch(void* const* d_in, const int* in_sizes, int n_in,
                              void* d_out, int out_size, void* d_ws, size_t ws_size,
                              hipStream_t stream)
{
    const float* act  = (const float*)d_in[0];
    const float* mask = (const float*)d_in[1];
    const float* ln_g = (const float*)d_in[2];
    const float* ln_b = (const float*)d_in[3];
    const float* Wl   = (const float*)d_in[4];
    const float* bl   = (const float*)d_in[5];
    const float* Wr   = (const float*)d_in[6];
    const float* br   = (const float*)d_in[7];
    const float* Wgl  = (const float*)d_in[8];
    const float* bgl  = (const float*)d_in[9];
    const float* Wgr  = (const float*)d_in[10];
    const float* bgr  = (const float*)d_in[11];
    const float* cg   = (const float*)d_in[12];
    const float* cb   = (const float*)d_in[13];
    const float* Wo   = (const float*)d_in[14];
    const float* bo   = (const float*)d_in[15];
    const float* Wg   = (const float*)d_in[16];
    const float* bg   = (const float*)d_in[17];
    float* outp = (float*)d_out;

    // workspace (ushorts): leftT | rightT | gate (CDIM*NN each) | wt 6*16384 |
    //                      tri bf16 CDIM*NN   => ~151 MB total
    ushort_t* ws16   = (ushort_t*)d_ws;
    ushort_t* leftT  = ws16;
    ushort_t* rightT = ws16 + (size_t)CDIM * NN;
    ushort_t* gate   = ws16 + (size_t)2 * CDIM * NN;
    ushort_t* wt     = ws16 + (size_t)3 * CDIM * NN;
    ushort_t* triB   = ws16 + (size_t)3 * CDIM * NN + 6 * 16384;

    wconv6<<<6, 256, 0, stream>>>(Wl, Wr, Wgl, Wgr, Wg, Wo, wt);
    proj_kernel<<<NN / 64, 256, 0, stream>>>(act, mask, ln_g, ln_b,
                                             bl, bgl, br, bgr, bg,
                                             wt, leftT, rightT, gate);
    tri_kernel<<<dim3(9, 128), 256, 0, stream>>>(leftT, rightT, triB);
    out_kernel<<<NN / 64, 256, 0, stream>>>(triB, cg, cb, wt + 5 * 16384, bo,
                                            gate, outp);
}